// Round 1
// baseline (991.015 us; speedup 1.0000x reference)
//
#include <hip/hip_runtime.h>
#include <hip/hip_bf16.h>
#include <math.h>

// Problem constants
#define L_SEQ 4096
#define CDIM  512
#define NH    8
#define NKV   2
#define HD    64
#define KVREP 4          // NH / NKV
#define SCALE 0.125f     // 1/sqrt(64)
#define EPS   1e-6f

// ---------------------------------------------------------------------------
// Generic fp32 NT GEMM: C[M][N] = A[M][K] * B[N][K]^T
// BM=BN=64, BK=16, 256 threads, 4x4 micro-tile per thread.
// ---------------------------------------------------------------------------
__global__ __launch_bounds__(256) void gemm_nt(const float* __restrict__ A,
                                               const float* __restrict__ B,
                                               float* __restrict__ C,
                                               int M, int N, int K) {
    __shared__ float As[16][65];
    __shared__ float Bs[16][65];
    const int tid = threadIdx.x;
    const int tx = tid & 15, ty = tid >> 4;
    const int m0 = blockIdx.y * 64, n0 = blockIdx.x * 64;

    float acc[4][4] = {};

    for (int k0 = 0; k0 < K; k0 += 16) {
        // Load 64x16 A tile and 64x16 B tile (float4 per thread each)
        {
            const int r  = tid >> 2;           // 0..63
            const int c4 = (tid & 3) << 2;     // 0,4,8,12
            const float4 av = *reinterpret_cast<const float4*>(
                &A[(size_t)(m0 + r) * K + k0 + c4]);
            As[c4 + 0][r] = av.x; As[c4 + 1][r] = av.y;
            As[c4 + 2][r] = av.z; As[c4 + 3][r] = av.w;
            const float4 bv = *reinterpret_cast<const float4*>(
                &B[(size_t)(n0 + r) * K + k0 + c4]);
            Bs[c4 + 0][r] = bv.x; Bs[c4 + 1][r] = bv.y;
            Bs[c4 + 2][r] = bv.z; Bs[c4 + 3][r] = bv.w;
        }
        __syncthreads();
#pragma unroll
        for (int kk = 0; kk < 16; ++kk) {
            float a[4], b[4];
#pragma unroll
            for (int i = 0; i < 4; ++i) a[i] = As[kk][ty * 4 + i];
#pragma unroll
            for (int j = 0; j < 4; ++j) b[j] = Bs[kk][tx * 4 + j];
#pragma unroll
            for (int i = 0; i < 4; ++i)
#pragma unroll
                for (int j = 0; j < 4; ++j) acc[i][j] += a[i] * b[j];
        }
        __syncthreads();
    }

#pragma unroll
    for (int i = 0; i < 4; ++i) {
        float4 v = make_float4(acc[i][0], acc[i][1], acc[i][2], acc[i][3]);
        *reinterpret_cast<float4*>(&C[(size_t)(m0 + ty * 4 + i) * N + n0 + tx * 4]) = v;
    }
}

// ---------------------------------------------------------------------------
// Fused RMSNorm + RoPE, in place. One wave (64 lanes) per head-vector.
// q layout: [L][NH*64], k layout: [L][NKV*64]. 256 threads = 4 rows/block.
// ---------------------------------------------------------------------------
__global__ __launch_bounds__(256) void norm_rope(float* __restrict__ q,
                                                 float* __restrict__ k,
                                                 const float* __restrict__ qw,
                                                 const float* __restrict__ kw) {
    const int wid  = threadIdx.x >> 6;
    const int lane = threadIdx.x & 63;
    const long row = (long)blockIdx.x * 4 + wid;     // 0 .. 40960
    const long QROWS = (long)L_SEQ * NH;

    float* ptr;
    const float* w;
    int pos;
    if (row < QROWS) {
        pos = (int)(row >> 3);
        ptr = q + (size_t)pos * (NH * HD) + (int)(row & 7) * HD;
        w = qw;
    } else {
        const long r = row - QROWS;
        pos = (int)(r >> 1);
        ptr = k + (size_t)pos * (NKV * HD) + (int)(r & 1) * HD;
        w = kw;
    }

    float x = ptr[lane];
    float ss = x * x;
#pragma unroll
    for (int off = 32; off; off >>= 1) ss += __shfl_xor(ss, off);
    float xn = x * rsqrtf(ss * (1.0f / 64.0f) + EPS) * w[lane];

    // rotate-half partner (lane ^ 32)
    float xp = __shfl_xor(xn, 32);
    const int i = lane & 31;
    const float inv_freq = powf(10000.0f, -(float)i * (1.0f / 32.0f));
    float s, c;
    sincosf((float)pos * inv_freq, &s, &c);
    float out = (lane < 32) ? (xn * c - xp * s) : (xn * c + xp * s);
    ptr[lane] = out;
}

// ---------------------------------------------------------------------------
// Flash-style fp32 attention. One block per (64-row Q block, head).
// KV tiles of 64. Online softmax. P reuses K's LDS tile.
// q: [L][512], k/v: [L][128], out: [L][512] (head-interleaved).
// ---------------------------------------------------------------------------
__global__ __launch_bounds__(256) void attn_fwd(const float* __restrict__ q,
                                                const float* __restrict__ k,
                                                const float* __restrict__ v,
                                                float* __restrict__ o) {
    __shared__ float Qs[64][65];
    __shared__ float KPs[64][65];   // K tile, reused for P
    __shared__ float Vs[64][65];

    const int tid = threadIdx.x;
    const int tx = tid & 15, ty = tid >> 4;
    const int q0 = blockIdx.x * 64;
    const int h  = blockIdx.y;
    const int hkv = h >> 2;

    // Load Q tile (64x64)
    {
        const int r = tid >> 2;
        const int cb = (tid & 3) * 16;
        const float* qp = q + (size_t)(q0 + r) * CDIM + h * HD + cb;
#pragma unroll
        for (int jj = 0; jj < 4; ++jj) {
            float4 qv = *reinterpret_cast<const float4*>(qp + jj * 4);
            Qs[r][cb + jj * 4 + 0] = qv.x; Qs[r][cb + jj * 4 + 1] = qv.y;
            Qs[r][cb + jj * 4 + 2] = qv.z; Qs[r][cb + jj * 4 + 3] = qv.w;
        }
    }

    float o_acc[4][4] = {};
    float m_i[4], l_i[4];
#pragma unroll
    for (int i = 0; i < 4; ++i) { m_i[i] = -INFINITY; l_i[i] = 0.0f; }

    for (int kv0 = 0; kv0 < L_SEQ; kv0 += 64) {
        __syncthreads();   // previous PV readers done before overwrite
        // Load K,V tiles
        {
            const int r  = tid >> 2;
            const int cb = (tid & 3) * 16;
            const float* kp = k + (size_t)(kv0 + r) * (NKV * HD) + hkv * HD + cb;
            const float* vp = v + (size_t)(kv0 + r) * (NKV * HD) + hkv * HD + cb;
#pragma unroll
            for (int jj = 0; jj < 4; ++jj) {
                float4 kv4 = *reinterpret_cast<const float4*>(kp + jj * 4);
                KPs[r][cb + jj * 4 + 0] = kv4.x; KPs[r][cb + jj * 4 + 1] = kv4.y;
                KPs[r][cb + jj * 4 + 2] = kv4.z; KPs[r][cb + jj * 4 + 3] = kv4.w;
                float4 vv4 = *reinterpret_cast<const float4*>(vp + jj * 4);
                Vs[r][cb + jj * 4 + 0] = vv4.x; Vs[r][cb + jj * 4 + 1] = vv4.y;
                Vs[r][cb + jj * 4 + 2] = vv4.z; Vs[r][cb + jj * 4 + 3] = vv4.w;
            }
        }
        __syncthreads();

        // S = scale * Q K^T   (4x4 per thread)
        float s[4][4] = {};
#pragma unroll 8
        for (int kk = 0; kk < 64; ++kk) {
            float a[4], b[4];
#pragma unroll
            for (int i = 0; i < 4; ++i) a[i] = Qs[ty * 4 + i][kk];
#pragma unroll
            for (int j = 0; j < 4; ++j) b[j] = KPs[tx * 4 + j][kk];
#pragma unroll
            for (int i = 0; i < 4; ++i)
#pragma unroll
                for (int j = 0; j < 4; ++j) s[i][j] += a[i] * b[j];
        }

        // Online softmax update
        float alpha[4];
#pragma unroll
        for (int i = 0; i < 4; ++i) {
            float rm = -INFINITY;
#pragma unroll
            for (int j = 0; j < 4; ++j) {
                s[i][j] *= SCALE;
                rm = fmaxf(rm, s[i][j]);
            }
#pragma unroll
            for (int off = 1; off < 16; off <<= 1)
                rm = fmaxf(rm, __shfl_xor(rm, off));
            const float mn = fmaxf(m_i[i], rm);
            alpha[i] = expf(m_i[i] - mn);
            m_i[i] = mn;
            float rowsum = 0.0f;
#pragma unroll
            for (int j = 0; j < 4; ++j) {
                const float p = expf(s[i][j] - mn);
                s[i][j] = p;
                rowsum += p;
            }
#pragma unroll
            for (int off = 1; off < 16; off <<= 1)
                rowsum += __shfl_xor(rowsum, off);
            l_i[i] = l_i[i] * alpha[i] + rowsum;
#pragma unroll
            for (int j = 0; j < 4; ++j) o_acc[i][j] *= alpha[i];
        }

        __syncthreads();   // all S readers done with KPs
        // Write P into KPs
#pragma unroll
        for (int i = 0; i < 4; ++i)
#pragma unroll
            for (int j = 0; j < 4; ++j)
                KPs[ty * 4 + i][tx * 4 + j] = s[i][j];
        __syncthreads();

        // O += P * V
#pragma unroll 8
        for (int kk = 0; kk < 64; ++kk) {
            float pv[4], vv[4];
#pragma unroll
            for (int i = 0; i < 4; ++i) pv[i] = KPs[ty * 4 + i][kk];
#pragma unroll
            for (int j = 0; j < 4; ++j) vv[j] = Vs[kk][tx * 4 + j];
#pragma unroll
            for (int i = 0; i < 4; ++i)
#pragma unroll
                for (int j = 0; j < 4; ++j) o_acc[i][j] += pv[i] * vv[j];
        }
    }

    // Epilogue: normalize, store to [L][NH*HD]
#pragma unroll
    for (int i = 0; i < 4; ++i) {
        const float inv = 1.0f / l_i[i];
        float4 ov = make_float4(o_acc[i][0] * inv, o_acc[i][1] * inv,
                                o_acc[i][2] * inv, o_acc[i][3] * inv);
        *reinterpret_cast<float4*>(
            &o[(size_t)(q0 + ty * 4 + i) * CDIM + h * HD + tx * 4]) = ov;
    }
}

// ---------------------------------------------------------------------------
extern "C" void kernel_launch(void* const* d_in, const int* in_sizes, int n_in,
                              void* d_out, int out_size, void* d_ws, size_t ws_size,
                              hipStream_t stream) {
    const float* x   = (const float*)d_in[0];   // [4096][512]
    const float* Wq  = (const float*)d_in[1];   // [512][512]
    const float* Wk  = (const float*)d_in[2];   // [128][512]
    const float* Wv  = (const float*)d_in[3];   // [128][512]
    const float* qnw = (const float*)d_in[4];   // [64]
    const float* knw = (const float*)d_in[5];   // [64]
    const float* Wo  = (const float*)d_in[6];   // [512][512]
    float* out = (float*)d_out;                 // [4096][512]

    float* qbuf = (float*)d_ws;                       // 4096*512
    float* kbuf = qbuf + (size_t)L_SEQ * CDIM;        // 4096*128
    float* vbuf = kbuf + (size_t)L_SEQ * (NKV * HD);  // 4096*128
    float* abuf = vbuf + (size_t)L_SEQ * (NKV * HD);  // 4096*512

    const dim3 blk(256);

    // QKV projections
    gemm_nt<<<dim3(CDIM / 64, L_SEQ / 64), blk, 0, stream>>>(x, Wq, qbuf, L_SEQ, CDIM, CDIM);
    gemm_nt<<<dim3((NKV * HD) / 64, L_SEQ / 64), blk, 0, stream>>>(x, Wk, kbuf, L_SEQ, NKV * HD, CDIM);
    gemm_nt<<<dim3((NKV * HD) / 64, L_SEQ / 64), blk, 0, stream>>>(x, Wv, vbuf, L_SEQ, NKV * HD, CDIM);

    // RMSNorm + RoPE (q and k, in place)
    norm_rope<<<dim3((L_SEQ * (NH + NKV)) / 4), blk, 0, stream>>>(qbuf, kbuf, qnw, knw);

    // Attention
    attn_fwd<<<dim3(L_SEQ / 64, NH), blk, 0, stream>>>(qbuf, kbuf, vbuf, abuf);

    // Output projection
    gemm_nt<<<dim3(CDIM / 64, L_SEQ / 64), blk, 0, stream>>>(abuf, Wo, out, L_SEQ, CDIM, CDIM);
}

// Round 2
// 475.586 us; speedup vs baseline: 2.0838x; 2.0838x over previous
//
#include <hip/hip_runtime.h>
#include <hip/hip_bf16.h>
#include <math.h>

// Problem constants
#define L_SEQ 4096
#define CDIM  512
#define NH    8
#define NKV   2
#define HD    64
#define SCALE 0.125f     // 1/sqrt(64)
#define EPS   1e-6f

using short8 = __attribute__((ext_vector_type(8))) short;
using f32x4  = __attribute__((ext_vector_type(4))) float;
typedef unsigned short ushort_t;

// RNE float -> bf16 bits
__device__ __forceinline__ ushort_t f2bf(float f) {
    union { float f; unsigned u; } c; c.f = f;
    unsigned r = c.u + 0x7FFF + ((c.u >> 16) & 1);
    return (ushort_t)(r >> 16);
}

// ---------------------------------------------------------------------------
// Generic fp32 NT GEMM: C[M][N] = A[M][K] * B[N][K]^T   (unchanged fp32 path)
// ---------------------------------------------------------------------------
__global__ __launch_bounds__(256) void gemm_nt(const float* __restrict__ A,
                                               const float* __restrict__ B,
                                               float* __restrict__ C,
                                               int M, int N, int K) {
    __shared__ float As[16][65];
    __shared__ float Bs[16][65];
    const int tid = threadIdx.x;
    const int tx = tid & 15, ty = tid >> 4;
    const int m0 = blockIdx.y * 64, n0 = blockIdx.x * 64;

    float acc[4][4] = {};

    for (int k0 = 0; k0 < K; k0 += 16) {
        {
            const int r  = tid >> 2;
            const int c4 = (tid & 3) << 2;
            const float4 av = *reinterpret_cast<const float4*>(
                &A[(size_t)(m0 + r) * K + k0 + c4]);
            As[c4 + 0][r] = av.x; As[c4 + 1][r] = av.y;
            As[c4 + 2][r] = av.z; As[c4 + 3][r] = av.w;
            const float4 bv = *reinterpret_cast<const float4*>(
                &B[(size_t)(n0 + r) * K + k0 + c4]);
            Bs[c4 + 0][r] = bv.x; Bs[c4 + 1][r] = bv.y;
            Bs[c4 + 2][r] = bv.z; Bs[c4 + 3][r] = bv.w;
        }
        __syncthreads();
#pragma unroll
        for (int kk = 0; kk < 16; ++kk) {
            float a[4], b[4];
#pragma unroll
            for (int i = 0; i < 4; ++i) a[i] = As[kk][ty * 4 + i];
#pragma unroll
            for (int j = 0; j < 4; ++j) b[j] = Bs[kk][tx * 4 + j];
#pragma unroll
            for (int i = 0; i < 4; ++i)
#pragma unroll
                for (int j = 0; j < 4; ++j) acc[i][j] += a[i] * b[j];
        }
        __syncthreads();
    }

#pragma unroll
    for (int i = 0; i < 4; ++i) {
        float4 v = make_float4(acc[i][0], acc[i][1], acc[i][2], acc[i][3]);
        *reinterpret_cast<float4*>(&C[(size_t)(m0 + ty * 4 + i) * N + n0 + tx * 4]) = v;
    }
}

// ---------------------------------------------------------------------------
// Fused RMSNorm + RoPE; reads fp32 q/k, writes bf16 q/k.
// One wave per head-vector. 256 threads = 4 rows/block.
// ---------------------------------------------------------------------------
__global__ __launch_bounds__(256) void norm_rope(const float* __restrict__ q,
                                                 const float* __restrict__ k,
                                                 const float* __restrict__ qw,
                                                 const float* __restrict__ kw,
                                                 ushort_t* __restrict__ qb,
                                                 ushort_t* __restrict__ kb) {
    const int wid  = threadIdx.x >> 6;
    const int lane = threadIdx.x & 63;
    const long row = (long)blockIdx.x * 4 + wid;
    const long QROWS = (long)L_SEQ * NH;

    const float* ptr;
    ushort_t* optr;
    const float* w;
    int pos;
    if (row < QROWS) {
        pos = (int)(row >> 3);
        const size_t off = (size_t)pos * (NH * HD) + (int)(row & 7) * HD;
        ptr = q + off; optr = qb + off;
        w = qw;
    } else {
        const long r = row - QROWS;
        pos = (int)(r >> 1);
        const size_t off = (size_t)pos * (NKV * HD) + (int)(r & 1) * HD;
        ptr = k + off; optr = kb + off;
        w = kw;
    }

    float x = ptr[lane];
    float ss = x * x;
#pragma unroll
    for (int off = 32; off; off >>= 1) ss += __shfl_xor(ss, off);
    float xn = x * rsqrtf(ss * (1.0f / 64.0f) + EPS) * w[lane];

    float xp = __shfl_xor(xn, 32);
    const int i = lane & 31;
    const float inv_freq = powf(10000.0f, -(float)i * (1.0f / 32.0f));
    float s, c;
    sincosf((float)pos * inv_freq, &s, &c);
    float out = (lane < 32) ? (xn * c - xp * s) : (xn * c + xp * s);
    optr[lane] = f2bf(out);
}

// ---------------------------------------------------------------------------
// V fp32 [4096][128] -> transposed bf16 [128][4096]
// ---------------------------------------------------------------------------
__global__ __launch_bounds__(256) void v_transpose_bf16(const float* __restrict__ v,
                                                        ushort_t* __restrict__ vt) {
    __shared__ float tt[64][65];
    const int c0 = blockIdx.x * 64;   // feature
    const int r0 = blockIdx.y * 64;   // position
    const int tid = threadIdx.x;

    {
        const int rr = tid >> 4;
        const int cc = (tid & 15) << 2;
#pragma unroll
        for (int i = 0; i < 4; ++i) {
            const int row = rr + i * 16;
            const float4 val = *reinterpret_cast<const float4*>(
                &v[(size_t)(r0 + row) * (NKV * HD) + c0 + cc]);
            tt[row][cc + 0] = val.x; tt[row][cc + 1] = val.y;
            tt[row][cc + 2] = val.z; tt[row][cc + 3] = val.w;
        }
    }
    __syncthreads();
    {
        const int ocol = tid & 63;
        const int ob = tid >> 6;
#pragma unroll
        for (int i = 0; i < 16; ++i) {
            const int orow = ob * 16 + i;
            vt[(size_t)(c0 + orow) * L_SEQ + r0 + ocol] = f2bf(tt[ocol][orow]);
        }
    }
}

// ---------------------------------------------------------------------------
// Flash attention, bf16 MFMA (16x16x32). 4 waves/block, each wave owns 16
// q-rows, fully independent (wave-private P buffer in LDS, no barriers).
// qb: [L][512] bf16, kb: [L][128] bf16, vtb: [128][L] bf16, o: [L][512] f32.
// ---------------------------------------------------------------------------
__global__ __launch_bounds__(256) void attn_mfma(const ushort_t* __restrict__ qb,
                                                 const ushort_t* __restrict__ kb,
                                                 const ushort_t* __restrict__ vtb,
                                                 float* __restrict__ o) {
    // per-wave P buffer: 16 rows x 160 bytes (64 bf16 + pad), XOR-swizzled
    __shared__ short Plds[4 * 16 * 80];
    const int tid = threadIdx.x;
    const int w = tid >> 6, lane = tid & 63;
    const int g = lane >> 4, r16 = lane & 15;
    const int h = blockIdx.y, hkv = h >> 2;
    const int qbase = blockIdx.x * 64 + w * 16;

    char* myP = reinterpret_cast<char*>(Plds) + w * (16 * 160);

    // Q fragments (A operand): row = r16, k = ks*32 + g*8 + j
    short8 aq[2];
#pragma unroll
    for (int ks = 0; ks < 2; ++ks)
        aq[ks] = *reinterpret_cast<const short8*>(
            &qb[(size_t)(qbase + r16) * CDIM + h * HD + ks * 32 + g * 8]);

    f32x4 oacc[4] = {};
    float m_i[4], l_i[4];
#pragma unroll
    for (int j = 0; j < 4; ++j) { m_i[j] = -INFINITY; l_i[j] = 0.0f; }

    for (int kv0 = 0; kv0 < L_SEQ; kv0 += 64) {
        // ---- S = Q K^T (8 MFMA) — K loaded straight from global (L2-hot)
        f32x4 sacc[4] = {};
#pragma unroll
        for (int t = 0; t < 4; ++t) {
#pragma unroll
            for (int ks = 0; ks < 2; ++ks) {
                const short8 bk = *reinterpret_cast<const short8*>(
                    &kb[(size_t)(kv0 + t * 16 + r16) * (NKV * HD) + hkv * HD + ks * 32 + g * 8]);
                sacc[t] = __builtin_amdgcn_mfma_f32_16x16x32_bf16(aq[ks], bk, sacc[t], 0, 0, 0);
            }
        }

        // ---- online softmax. Lane's rows: 4*g + j; 16-lane-group reductions.
        float alpha[4];
#pragma unroll
        for (int j = 0; j < 4; ++j) {
            float rm = fmaxf(fmaxf(sacc[0][j], sacc[1][j]),
                             fmaxf(sacc[2][j], sacc[3][j]));
#pragma unroll
            for (int off = 1; off < 16; off <<= 1)
                rm = fmaxf(rm, __shfl_xor(rm, off));
            rm *= SCALE;
            const float mn = fmaxf(m_i[j], rm);
            alpha[j] = __expf(m_i[j] - mn);
            m_i[j] = mn;
            float rs = 0.0f;
#pragma unroll
            for (int t = 0; t < 4; ++t) {
                const float p = __expf(sacc[t][j] * SCALE - mn);
                sacc[t][j] = p;
                rs += p;
            }
#pragma unroll
            for (int off = 1; off < 16; off <<= 1)
                rs += __shfl_xor(rs, off);
            l_i[j] = l_i[j] * alpha[j] + rs;
        }

        // ---- P (bf16) -> wave-private LDS (swizzled), rescale O
#pragma unroll
        for (int j = 0; j < 4; ++j) {
            const int row = g * 4 + j;
            char* rp = myP + row * 160;
            const int sw = (row & 7) << 4;
#pragma unroll
            for (int t = 0; t < 4; ++t) {
                const int byte = ((t * 16 + r16) * 2) ^ sw;
                *reinterpret_cast<short*>(rp + byte) = (short)f2bf(sacc[t][j]);
            }
            oacc[0][j] *= alpha[j]; oacc[1][j] *= alpha[j];
            oacc[2][j] *= alpha[j]; oacc[3][j] *= alpha[j];
        }

        // ---- O += P V (8 MFMA) — V^T loaded straight from global
#pragma unroll
        for (int ks = 0; ks < 2; ++ks) {
            short8 ap;
            __builtin_memcpy(&ap,
                myP + r16 * 160 + ((ks * 64 + g * 16) ^ ((r16 & 7) << 4)), 16);
#pragma unroll
            for (int t = 0; t < 4; ++t) {
                const short8 bv = *reinterpret_cast<const short8*>(
                    &vtb[(size_t)(hkv * HD + t * 16 + r16) * L_SEQ + kv0 + ks * 32 + g * 8]);
                oacc[t] = __builtin_amdgcn_mfma_f32_16x16x32_bf16(ap, bv, oacc[t], 0, 0, 0);
            }
        }
    }

    // ---- epilogue: normalize, store fp32
#pragma unroll
    for (int j = 0; j < 4; ++j) {
        const float inv = 1.0f / l_i[j];
        const int row = qbase + g * 4 + j;
#pragma unroll
        for (int t = 0; t < 4; ++t)
            o[(size_t)row * CDIM + h * HD + t * 16 + r16] = oacc[t][j] * inv;
    }
}

// ---------------------------------------------------------------------------
extern "C" void kernel_launch(void* const* d_in, const int* in_sizes, int n_in,
                              void* d_out, int out_size, void* d_ws, size_t ws_size,
                              hipStream_t stream) {
    const float* x   = (const float*)d_in[0];   // [4096][512]
    const float* Wq  = (const float*)d_in[1];   // [512][512]
    const float* Wk  = (const float*)d_in[2];   // [128][512]
    const float* Wv  = (const float*)d_in[3];   // [128][512]
    const float* qnw = (const float*)d_in[4];   // [64]
    const float* knw = (const float*)d_in[5];   // [64]
    const float* Wo  = (const float*)d_in[6];   // [512][512]
    float* out = (float*)d_out;                 // [4096][512]

    // workspace layout (18 MB total)
    float* qbuf = (float*)d_ws;                        // 4096*512 f32 (8 MB) — reused as attn out
    float* kbuf = qbuf + (size_t)L_SEQ * CDIM;         // 4096*128 f32 (2 MB)
    float* vbuf = kbuf + (size_t)L_SEQ * (NKV * HD);   // 4096*128 f32 (2 MB)
    ushort_t* qb  = (ushort_t*)(vbuf + (size_t)L_SEQ * (NKV * HD)); // 4 MB
    ushort_t* kb  = qb + (size_t)L_SEQ * CDIM;                      // 1 MB
    ushort_t* vtb = kb + (size_t)L_SEQ * (NKV * HD);                // 1 MB
    float* abuf = qbuf;  // attention output aliases qbuf (dead after norm_rope)

    const dim3 blk(256);

    // QKV projections (fp32)
    gemm_nt<<<dim3(CDIM / 64, L_SEQ / 64), blk, 0, stream>>>(x, Wq, qbuf, L_SEQ, CDIM, CDIM);
    gemm_nt<<<dim3((NKV * HD) / 64, L_SEQ / 64), blk, 0, stream>>>(x, Wk, kbuf, L_SEQ, NKV * HD, CDIM);
    gemm_nt<<<dim3((NKV * HD) / 64, L_SEQ / 64), blk, 0, stream>>>(x, Wv, vbuf, L_SEQ, NKV * HD, CDIM);

    // RMSNorm + RoPE -> bf16
    norm_rope<<<dim3((L_SEQ * (NH + NKV)) / 4), blk, 0, stream>>>(qbuf, kbuf, qnw, knw, qb, kb);

    // V -> transposed bf16
    v_transpose_bf16<<<dim3((NKV * HD) / 64, L_SEQ / 64), blk, 0, stream>>>(vbuf, vtb);

    // Attention (bf16 MFMA)
    attn_mfma<<<dim3(L_SEQ / 64, NH), blk, 0, stream>>>(qb, kb, vtb, abuf);

    // Output projection (fp32)
    gemm_nt<<<dim3(CDIM / 64, L_SEQ / 64), blk, 0, stream>>>(abuf, Wo, out, L_SEQ, CDIM, CDIM);
}

// Round 3
// 324.374 us; speedup vs baseline: 3.0552x; 1.4662x over previous
//
#include <hip/hip_runtime.h>
#include <hip/hip_bf16.h>
#include <math.h>

// Problem constants
#define L_SEQ 4096
#define CDIM  512
#define NH    8
#define NKV   2
#define HD    64
#define SCALE 0.125f     // 1/sqrt(64), folded into Q in norm_rope
#define EPS   1e-6f

using short8 = __attribute__((ext_vector_type(8))) short;
using f32x4  = __attribute__((ext_vector_type(4))) float;
typedef unsigned short ushort_t;

// RNE float -> bf16 bits
__device__ __forceinline__ ushort_t f2bf(float f) {
    union { float f; unsigned u; } c; c.f = f;
    unsigned r = c.u + 0x7FFF + ((c.u >> 16) & 1);
    return (ushort_t)(r >> 16);
}

// async global->LDS, 16B per lane; LDS dest = uniform base + lane*16
#define GLOAD_LDS16(g, l)                                                  \
    __builtin_amdgcn_global_load_lds(                                      \
        (const __attribute__((address_space(1))) unsigned int*)(g),        \
        (__attribute__((address_space(3))) unsigned int*)(l), 16, 0, 0)

// ---------------------------------------------------------------------------
// Generic fp32 NT GEMM: C[M][N] = A[M][K] * B[N][K]^T
// ---------------------------------------------------------------------------
__global__ __launch_bounds__(256) void gemm_nt(const float* __restrict__ A,
                                               const float* __restrict__ B,
                                               float* __restrict__ C,
                                               int M, int N, int K) {
    __shared__ float As[16][65];
    __shared__ float Bs[16][65];
    const int tid = threadIdx.x;
    const int tx = tid & 15, ty = tid >> 4;
    const int m0 = blockIdx.y * 64, n0 = blockIdx.x * 64;

    float acc[4][4] = {};

    for (int k0 = 0; k0 < K; k0 += 16) {
        {
            const int r  = tid >> 2;
            const int c4 = (tid & 3) << 2;
            const float4 av = *reinterpret_cast<const float4*>(
                &A[(size_t)(m0 + r) * K + k0 + c4]);
            As[c4 + 0][r] = av.x; As[c4 + 1][r] = av.y;
            As[c4 + 2][r] = av.z; As[c4 + 3][r] = av.w;
            const float4 bv = *reinterpret_cast<const float4*>(
                &B[(size_t)(n0 + r) * K + k0 + c4]);
            Bs[c4 + 0][r] = bv.x; Bs[c4 + 1][r] = bv.y;
            Bs[c4 + 2][r] = bv.z; Bs[c4 + 3][r] = bv.w;
        }
        __syncthreads();
#pragma unroll
        for (int kk = 0; kk < 16; ++kk) {
            float a[4], b[4];
#pragma unroll
            for (int i = 0; i < 4; ++i) a[i] = As[kk][ty * 4 + i];
#pragma unroll
            for (int j = 0; j < 4; ++j) b[j] = Bs[kk][tx * 4 + j];
#pragma unroll
            for (int i = 0; i < 4; ++i)
#pragma unroll
                for (int j = 0; j < 4; ++j) acc[i][j] += a[i] * b[j];
        }
        __syncthreads();
    }

#pragma unroll
    for (int i = 0; i < 4; ++i) {
        float4 v = make_float4(acc[i][0], acc[i][1], acc[i][2], acc[i][3]);
        *reinterpret_cast<float4*>(&C[(size_t)(m0 + ty * 4 + i) * N + n0 + tx * 4]) = v;
    }
}

// ---------------------------------------------------------------------------
// Fused RMSNorm + RoPE; reads fp32 q/k, writes bf16 q/k.
// Q is pre-scaled by 1/sqrt(HD) (exact power of 2 in bf16).
// ---------------------------------------------------------------------------
__global__ __launch_bounds__(256) void norm_rope(const float* __restrict__ q,
                                                 const float* __restrict__ k,
                                                 const float* __restrict__ qw,
                                                 const float* __restrict__ kw,
                                                 ushort_t* __restrict__ qb,
                                                 ushort_t* __restrict__ kb) {
    const int wid  = threadIdx.x >> 6;
    const int lane = threadIdx.x & 63;
    const long row = (long)blockIdx.x * 4 + wid;
    const long QROWS = (long)L_SEQ * NH;

    const float* ptr;
    ushort_t* optr;
    const float* w;
    int pos;
    const bool isq = (row < QROWS);
    if (isq) {
        pos = (int)(row >> 3);
        const size_t off = (size_t)pos * (NH * HD) + (int)(row & 7) * HD;
        ptr = q + off; optr = qb + off;
        w = qw;
    } else {
        const long r = row - QROWS;
        pos = (int)(r >> 1);
        const size_t off = (size_t)pos * (NKV * HD) + (int)(r & 1) * HD;
        ptr = k + off; optr = kb + off;
        w = kw;
    }

    float x = ptr[lane];
    float ss = x * x;
#pragma unroll
    for (int off = 32; off; off >>= 1) ss += __shfl_xor(ss, off);
    float xn = x * rsqrtf(ss * (1.0f / 64.0f) + EPS) * w[lane];

    float xp = __shfl_xor(xn, 32);
    const int i = lane & 31;
    const float inv_freq = powf(10000.0f, -(float)i * (1.0f / 32.0f));
    float s, c;
    sincosf((float)pos * inv_freq, &s, &c);
    float out = (lane < 32) ? (xn * c - xp * s) : (xn * c + xp * s);
    if (isq) out *= SCALE;
    optr[lane] = f2bf(out);
}

// ---------------------------------------------------------------------------
// V fp32 [4096][128] -> transposed bf16 [128][4096]
// ---------------------------------------------------------------------------
__global__ __launch_bounds__(256) void v_transpose_bf16(const float* __restrict__ v,
                                                        ushort_t* __restrict__ vt) {
    __shared__ float tt[64][65];
    const int c0 = blockIdx.x * 64;   // feature
    const int r0 = blockIdx.y * 64;   // position
    const int tid = threadIdx.x;

    {
        const int rr = tid >> 4;
        const int cc = (tid & 15) << 2;
#pragma unroll
        for (int i = 0; i < 4; ++i) {
            const int row = rr + i * 16;
            const float4 val = *reinterpret_cast<const float4*>(
                &v[(size_t)(r0 + row) * (NKV * HD) + c0 + cc]);
            tt[row][cc + 0] = val.x; tt[row][cc + 1] = val.y;
            tt[row][cc + 2] = val.z; tt[row][cc + 3] = val.w;
        }
    }
    __syncthreads();
    {
        const int ocol = tid & 63;
        const int ob = tid >> 6;
#pragma unroll
        for (int i = 0; i < 16; ++i) {
            const int orow = ob * 16 + i;
            vt[(size_t)(c0 + orow) * L_SEQ + r0 + ocol] = f2bf(tt[ocol][orow]);
        }
    }
}

// ---------------------------------------------------------------------------
// Flash attention, bf16 MFMA 16x16x32. 4 waves/block, 64 q-rows/block.
// K/V tiles (64 kv x 64 feat) staged in LDS via global_load_lds, double-
// buffered; linear LDS dest + inverse-swizzled global source + swizzled
// ds_read (byte ^= (row&7)<<4) for bank-conflict-minimal b128 reads.
// qb: [L][512] bf16 (pre-scaled), kb: [L][128] bf16, vtb: [128][L] bf16.
// ---------------------------------------------------------------------------
__global__ __launch_bounds__(256) void attn_mfma(const ushort_t* __restrict__ qb,
                                                 const ushort_t* __restrict__ kb,
                                                 const ushort_t* __restrict__ vtb,
                                                 float* __restrict__ o) {
    __shared__ short Ks[2][4096];           // [64 kv rows][64 feat] bf16, 8KB each
    __shared__ short Vs[2][4096];           // [64 feat rows][64 kv]  bf16
    __shared__ short Plds[4 * 16 * 80];     // per-wave P, 16 x 160B, swizzled

    const int tid = threadIdx.x;
    const int w = tid >> 6, lane = tid & 63;
    const int g = lane >> 4, r16 = lane & 15;
    const int h = blockIdx.y, hkv = h >> 2;
    const int qbase = blockIdx.x * 64 + w * 16;

    char* myP = reinterpret_cast<char*>(Plds) + w * (16 * 160);
    const int r7sw = (r16 & 7) << 4;

    // staging geometry: wave w owns chunks c0,c1 (8 rows x 128B each)
    const int lrow = lane >> 3;                 // 0..7 (row within chunk)
    const int swzb = ((lane & 7) ^ lrow) << 4;  // inverse-swizzled byte in 128B window
    const int c0 = w * 2, c1 = w * 2 + 1;

    // per-lane global source bases at kv tile 0
    const char* kgA = (const char*)kb + (size_t)(c0 * 8 + lrow) * (NKV * HD * 2)
                      + hkv * (HD * 2) + swzb;
    const char* kgB = kgA + 8 * (NKV * HD * 2);
    const char* vgA = (const char*)vtb + (size_t)(hkv * HD + c0 * 8 + lrow) * (L_SEQ * 2)
                      + swzb;
    const char* vgB = vgA + 8 * (size_t)(L_SEQ * 2);

    // Q fragments (A operand): row = r16, k = ks*32 + g*8 + j
    short8 aq[2];
#pragma unroll
    for (int ks = 0; ks < 2; ++ks)
        aq[ks] = *reinterpret_cast<const short8*>(
            &qb[(size_t)(qbase + r16) * CDIM + h * HD + ks * 32 + g * 8]);

    // stage tile 0 into buffer 0
    GLOAD_LDS16(kgA, (char*)Ks[0] + c0 * 1024);
    GLOAD_LDS16(kgB, (char*)Ks[0] + c1 * 1024);
    GLOAD_LDS16(vgA, (char*)Vs[0] + c0 * 1024);
    GLOAD_LDS16(vgB, (char*)Vs[0] + c1 * 1024);
    __syncthreads();

    f32x4 oacc[4] = {};
    float m_i[4], l_i[4];
#pragma unroll
    for (int j = 0; j < 4; ++j) { m_i[j] = -INFINITY; l_i[j] = 0.0f; }

    int cur = 0;
    for (int it = 0; it < L_SEQ / 64; ++it) {
        // ---- prefetch next tile into other buffer
        if (it + 1 < L_SEQ / 64) {
            const size_t ko = (size_t)(it + 1) * 64 * (NKV * HD * 2);
            const size_t vo = (size_t)(it + 1) * 128;
            char* kd = (char*)Ks[cur ^ 1];
            char* vd = (char*)Vs[cur ^ 1];
            GLOAD_LDS16(kgA + ko, kd + c0 * 1024);
            GLOAD_LDS16(kgB + ko, kd + c1 * 1024);
            GLOAD_LDS16(vgA + vo, vd + c0 * 1024);
            GLOAD_LDS16(vgB + vo, vd + c1 * 1024);
        }

        const char* kt = (const char*)Ks[cur];
        const char* vt = (const char*)Vs[cur];

        // ---- S = Q K^T (8 MFMA), K fragments from swizzled LDS
        f32x4 sacc[4] = {};
#pragma unroll
        for (int t = 0; t < 4; ++t) {
#pragma unroll
            for (int ks = 0; ks < 2; ++ks) {
                short8 bk;
                __builtin_memcpy(&bk,
                    kt + (t * 16 + r16) * 128 + ((ks * 64 + g * 16) ^ r7sw), 16);
                sacc[t] = __builtin_amdgcn_mfma_f32_16x16x32_bf16(aq[ks], bk, sacc[t], 0, 0, 0);
            }
        }

        // ---- online softmax (Q pre-scaled). Lane's rows: 4*g + j.
        float alpha[4];
#pragma unroll
        for (int j = 0; j < 4; ++j) {
            float rm = fmaxf(fmaxf(sacc[0][j], sacc[1][j]),
                             fmaxf(sacc[2][j], sacc[3][j]));
#pragma unroll
            for (int off = 1; off < 16; off <<= 1)
                rm = fmaxf(rm, __shfl_xor(rm, off));
            const float mn = fmaxf(m_i[j], rm);
            alpha[j] = __expf(m_i[j] - mn);
            m_i[j] = mn;
            float rs = 0.0f;
#pragma unroll
            for (int t = 0; t < 4; ++t) {
                const float p = __expf(sacc[t][j] - mn);
                sacc[t][j] = p;
                rs += p;
            }
#pragma unroll
            for (int off = 1; off < 16; off <<= 1)
                rs += __shfl_xor(rs, off);
            l_i[j] = l_i[j] * alpha[j] + rs;
        }

        // ---- P (bf16) -> wave-private LDS (swizzled), rescale O
#pragma unroll
        for (int j = 0; j < 4; ++j) {
            const int row = g * 4 + j;
            char* rp = myP + row * 160;
            const int sw = (row & 7) << 4;
#pragma unroll
            for (int t = 0; t < 4; ++t) {
                const int byte = ((t * 16 + r16) * 2) ^ sw;
                *reinterpret_cast<short*>(rp + byte) = (short)f2bf(sacc[t][j]);
            }
            oacc[0][j] *= alpha[j]; oacc[1][j] *= alpha[j];
            oacc[2][j] *= alpha[j]; oacc[3][j] *= alpha[j];
        }

        // ---- O += P V (8 MFMA), V fragments from swizzled LDS
#pragma unroll
        for (int ks = 0; ks < 2; ++ks) {
            short8 ap;
            __builtin_memcpy(&ap,
                myP + r16 * 160 + ((ks * 64 + g * 16) ^ ((r16 & 7) << 4)), 16);
#pragma unroll
            for (int t = 0; t < 4; ++t) {
                short8 bv;
                __builtin_memcpy(&bv,
                    vt + (t * 16 + r16) * 128 + ((ks * 64 + g * 16) ^ r7sw), 16);
                oacc[t] = __builtin_amdgcn_mfma_f32_16x16x32_bf16(ap, bv, oacc[t], 0, 0, 0);
            }
        }

        __syncthreads();   // staged loads landed; all waves done with buf[cur]
        cur ^= 1;
    }

    // ---- epilogue: normalize, store fp32
#pragma unroll
    for (int j = 0; j < 4; ++j) {
        const float inv = 1.0f / l_i[j];
        const int row = qbase + g * 4 + j;
#pragma unroll
        for (int t = 0; t < 4; ++t)
            o[(size_t)row * CDIM + h * HD + t * 16 + r16] = oacc[t][j] * inv;
    }
}

// ---------------------------------------------------------------------------
extern "C" void kernel_launch(void* const* d_in, const int* in_sizes, int n_in,
                              void* d_out, int out_size, void* d_ws, size_t ws_size,
                              hipStream_t stream) {
    const float* x   = (const float*)d_in[0];   // [4096][512]
    const float* Wq  = (const float*)d_in[1];   // [512][512]
    const float* Wk  = (const float*)d_in[2];   // [128][512]
    const float* Wv  = (const float*)d_in[3];   // [128][512]
    const float* qnw = (const float*)d_in[4];   // [64]
    const float* knw = (const float*)d_in[5];   // [64]
    const float* Wo  = (const float*)d_in[6];   // [512][512]
    float* out = (float*)d_out;                 // [4096][512]

    float* qbuf = (float*)d_ws;                        // 4096*512 f32 — reused as attn out
    float* kbuf = qbuf + (size_t)L_SEQ * CDIM;         // 4096*128 f32
    float* vbuf = kbuf + (size_t)L_SEQ * (NKV * HD);   // 4096*128 f32
    ushort_t* qb  = (ushort_t*)(vbuf + (size_t)L_SEQ * (NKV * HD)); // 4 MB
    ushort_t* kb  = qb + (size_t)L_SEQ * CDIM;                      // 1 MB
    ushort_t* vtb = kb + (size_t)L_SEQ * (NKV * HD);                // 1 MB
    float* abuf = qbuf;  // attention output aliases qbuf (dead after norm_rope)

    const dim3 blk(256);

    // QKV projections (fp32)
    gemm_nt<<<dim3(CDIM / 64, L_SEQ / 64), blk, 0, stream>>>(x, Wq, qbuf, L_SEQ, CDIM, CDIM);
    gemm_nt<<<dim3((NKV * HD) / 64, L_SEQ / 64), blk, 0, stream>>>(x, Wk, kbuf, L_SEQ, NKV * HD, CDIM);
    gemm_nt<<<dim3((NKV * HD) / 64, L_SEQ / 64), blk, 0, stream>>>(x, Wv, vbuf, L_SEQ, NKV * HD, CDIM);

    // RMSNorm + RoPE -> bf16 (Q pre-scaled by 1/8)
    norm_rope<<<dim3((L_SEQ * (NH + NKV)) / 4), blk, 0, stream>>>(qbuf, kbuf, qnw, knw, qb, kb);

    // V -> transposed bf16
    v_transpose_bf16<<<dim3((NKV * HD) / 64, L_SEQ / 64), blk, 0, stream>>>(vbuf, vtb);

    // Attention (bf16 MFMA, LDS-staged K/V)
    attn_mfma<<<dim3(L_SEQ / 64, NH), blk, 0, stream>>>(qb, kb, vtb, abuf);

    // Output projection (fp32)
    gemm_nt<<<dim3(CDIM / 64, L_SEQ / 64), blk, 0, stream>>>(abuf, Wo, out, L_SEQ, CDIM, CDIM);
}

// Round 4
// 136.476 us; speedup vs baseline: 7.2614x; 2.3768x over previous
//
#include <hip/hip_runtime.h>
#include <hip/hip_bf16.h>
#include <math.h>

// Problem constants
#define L_SEQ 4096
#define CDIM  512
#define NH    8
#define NKV   2
#define HD    64
#define EPS   1e-6f
// 1/sqrt(64) * log2(e), folded into Q at norm_rope so P = exp2(S) directly
#define QSCALE 0.18033688011f

using short8 = __attribute__((ext_vector_type(8))) short;
using f32x4  = __attribute__((ext_vector_type(4))) float;
typedef unsigned short ushort_t;

// RNE float -> bf16 bits
__device__ __forceinline__ ushort_t f2bf(float f) {
    union { float f; unsigned u; } c; c.f = f;
    unsigned r = c.u + 0x7FFF + ((c.u >> 16) & 1);
    return (ushort_t)(r >> 16);
}

// async global->LDS, 16B per lane; LDS dest = wave-uniform base + lane*16
#define GLOAD_LDS16(g, l)                                                  \
    __builtin_amdgcn_global_load_lds(                                      \
        (const __attribute__((address_space(1))) unsigned int*)(g),        \
        (__attribute__((address_space(3))) unsigned int*)(l), 16, 0, 0)

// ---------------------------------------------------------------------------
// f32 -> bf16 conversion for x and the 4 weights (one launch).
// Segment boundaries in elements (all multiples of 4).
// ---------------------------------------------------------------------------
__global__ __launch_bounds__(256) void cvt_bf16(const float* __restrict__ x,
                                                const float* __restrict__ wq,
                                                const float* __restrict__ wk,
                                                const float* __restrict__ wv,
                                                const float* __restrict__ wo,
                                                ushort_t* __restrict__ xb,
                                                ushort_t* __restrict__ wqb,
                                                ushort_t* __restrict__ wkb,
                                                ushort_t* __restrict__ wvb,
                                                ushort_t* __restrict__ wob) {
    const size_t i = ((size_t)blockIdx.x * 256 + threadIdx.x) << 2;
    const float* s; ushort_t* d; size_t o;
    if (i < 2097152)      { s = x;  d = xb;  o = i; }
    else if (i < 2359296) { s = wq; d = wqb; o = i - 2097152; }
    else if (i < 2424832) { s = wk; d = wkb; o = i - 2359296; }
    else if (i < 2490368) { s = wv; d = wvb; o = i - 2424832; }
    else                  { s = wo; d = wob; o = i - 2490368; }
    const float4 v = *reinterpret_cast<const float4*>(s + o);
    ushort_t r[4] = { f2bf(v.x), f2bf(v.y), f2bf(v.z), f2bf(v.w) };
    *reinterpret_cast<uint2*>(d + o) = *reinterpret_cast<const uint2*>(r);
}

// ---------------------------------------------------------------------------
// bf16 MFMA NT GEMM: C[M][N] = A[M][K] * B[N][K]^T, fp32 accumulate.
// BM=BN=BK=64, 256 threads (2x2 waves, 32x32 per wave), double-buffered LDS
// staged via global_load_lds with inverse-swizzled source + swizzled ds_read.
// ---------------------------------------------------------------------------
template<bool OUT_BF16>
__global__ __launch_bounds__(256) void gemm_bf16_nt(const ushort_t* __restrict__ A,
                                                    const ushort_t* __restrict__ B,
                                                    void* __restrict__ Cv,
                                                    int M, int N, int K) {
    __shared__ short As[2][4096];   // [64 rows][64 k] bf16, 8KB each
    __shared__ short Bs[2][4096];

    const int tid = threadIdx.x;
    const int w = tid >> 6, lane = tid & 63;
    const int g = lane >> 4, r16 = lane & 15;
    const int wr = w >> 1, wc = w & 1;
    const int m0 = blockIdx.y * 64, n0 = blockIdx.x * 64;
    const int r7sw = (r16 & 7) << 4;

    // staging: each wave owns 2 chunks (8 rows x 128B each) per matrix
    const int lrow = lane >> 3;
    const int swzb = ((lane & 7) ^ lrow) << 4;
    const int c0 = w * 2, c1 = w * 2 + 1;
    const size_t rowK2 = (size_t)K * 2;

    const char* agA = (const char*)A + (size_t)(m0 + c0 * 8 + lrow) * rowK2 + swzb;
    const char* agB = agA + 8 * rowK2;
    const char* bgA = (const char*)B + (size_t)(n0 + c0 * 8 + lrow) * rowK2 + swzb;
    const char* bgB = bgA + 8 * rowK2;

    // stage k-tile 0 into buffer 0
    GLOAD_LDS16(agA, (char*)As[0] + c0 * 1024);
    GLOAD_LDS16(agB, (char*)As[0] + c1 * 1024);
    GLOAD_LDS16(bgA, (char*)Bs[0] + c0 * 1024);
    GLOAD_LDS16(bgB, (char*)Bs[0] + c1 * 1024);
    __syncthreads();

    f32x4 acc[2][2] = {};
    const int NKIT = K >> 6;
    int cur = 0;
    for (int it = 0; it < NKIT; ++it) {
        if (it + 1 < NKIT) {
            const size_t ko = (size_t)(it + 1) * 128;   // 64 elems = 128B along row
            char* ad = (char*)As[cur ^ 1];
            char* bd = (char*)Bs[cur ^ 1];
            GLOAD_LDS16(agA + ko, ad + c0 * 1024);
            GLOAD_LDS16(agB + ko, ad + c1 * 1024);
            GLOAD_LDS16(bgA + ko, bd + c0 * 1024);
            GLOAD_LDS16(bgB + ko, bd + c1 * 1024);
        }
        const char* at = (const char*)As[cur];
        const char* bt = (const char*)Bs[cur];

        short8 af[2][2], bf[2][2];
#pragma unroll
        for (int t = 0; t < 2; ++t)
#pragma unroll
            for (int ks = 0; ks < 2; ++ks) {
                __builtin_memcpy(&af[t][ks],
                    at + (wr * 32 + t * 16 + r16) * 128 + ((ks * 64 + g * 16) ^ r7sw), 16);
                __builtin_memcpy(&bf[t][ks],
                    bt + (wc * 32 + t * 16 + r16) * 128 + ((ks * 64 + g * 16) ^ r7sw), 16);
            }
#pragma unroll
        for (int tm = 0; tm < 2; ++tm)
#pragma unroll
            for (int tn = 0; tn < 2; ++tn)
#pragma unroll
                for (int ks = 0; ks < 2; ++ks)
                    acc[tm][tn] = __builtin_amdgcn_mfma_f32_16x16x32_bf16(
                        af[tm][ks], bf[tn][ks], acc[tm][tn], 0, 0, 0);

        __syncthreads();
        cur ^= 1;
    }

#pragma unroll
    for (int tm = 0; tm < 2; ++tm)
#pragma unroll
        for (int tn = 0; tn < 2; ++tn)
#pragma unroll
            for (int jj = 0; jj < 4; ++jj) {
                const int row = m0 + wr * 32 + tm * 16 + g * 4 + jj;
                const int col = n0 + wc * 32 + tn * 16 + r16;
                if (OUT_BF16)
                    ((ushort_t*)Cv)[(size_t)row * N + col] = f2bf(acc[tm][tn][jj]);
                else
                    ((float*)Cv)[(size_t)row * N + col] = acc[tm][tn][jj];
            }
}

// ---------------------------------------------------------------------------
// Fused RMSNorm + RoPE; reads fp32 q/k, writes bf16 q/k.
// Q is pre-scaled by QSCALE = (1/8)*log2(e) so attn uses exp2 directly.
// ---------------------------------------------------------------------------
__global__ __launch_bounds__(256) void norm_rope(const float* __restrict__ q,
                                                 const float* __restrict__ k,
                                                 const float* __restrict__ qw,
                                                 const float* __restrict__ kw,
                                                 ushort_t* __restrict__ qb,
                                                 ushort_t* __restrict__ kb) {
    const int wid  = threadIdx.x >> 6;
    const int lane = threadIdx.x & 63;
    const long row = (long)blockIdx.x * 4 + wid;
    const long QROWS = (long)L_SEQ * NH;

    const float* ptr;
    ushort_t* optr;
    const float* w;
    int pos;
    const bool isq = (row < QROWS);
    if (isq) {
        pos = (int)(row >> 3);
        const size_t off = (size_t)pos * (NH * HD) + (int)(row & 7) * HD;
        ptr = q + off; optr = qb + off;
        w = qw;
    } else {
        const long r = row - QROWS;
        pos = (int)(r >> 1);
        const size_t off = (size_t)pos * (NKV * HD) + (int)(r & 1) * HD;
        ptr = k + off; optr = kb + off;
        w = kw;
    }

    float x = ptr[lane];
    float ss = x * x;
#pragma unroll
    for (int off = 32; off; off >>= 1) ss += __shfl_xor(ss, off);
    float xn = x * rsqrtf(ss * (1.0f / 64.0f) + EPS) * w[lane];

    float xp = __shfl_xor(xn, 32);
    const int i = lane & 31;
    const float inv_freq = powf(10000.0f, -(float)i * (1.0f / 32.0f));
    float s, c;
    sincosf((float)pos * inv_freq, &s, &c);
    float out = (lane < 32) ? (xn * c - xp * s) : (xn * c + xp * s);
    if (isq) out *= QSCALE;
    optr[lane] = f2bf(out);
}

// ---------------------------------------------------------------------------
// Flash attention, bf16 MFMA 16x16x32, NO-MAX softmax (logits bounded since
// q,k are RMS-normed; exp2 done in fp32, scale-free bf16 P storage).
// 4 waves/block, 64 q-rows/block, K/V double-buffered in LDS. Output bf16.
// ---------------------------------------------------------------------------
__global__ __launch_bounds__(256) void attn_mfma(const ushort_t* __restrict__ qb,
                                                 const ushort_t* __restrict__ kb,
                                                 const ushort_t* __restrict__ vtb,
                                                 ushort_t* __restrict__ o) {
    __shared__ short Ks[2][4096];           // [64 kv][64 feat] bf16
    __shared__ short Vs[2][4096];           // [64 feat][64 kv] bf16
    __shared__ short Plds[4 * 16 * 80];     // per-wave P, 16 x 160B, swizzled

    const int tid = threadIdx.x;
    const int w = tid >> 6, lane = tid & 63;
    const int g = lane >> 4, r16 = lane & 15;
    const int h = blockIdx.y, hkv = h >> 2;
    const int qbase = blockIdx.x * 64 + w * 16;

    char* myP = reinterpret_cast<char*>(Plds) + w * (16 * 160);
    const int r7sw = (r16 & 7) << 4;

    const int lrow = lane >> 3;
    const int swzb = ((lane & 7) ^ lrow) << 4;
    const int c0 = w * 2, c1 = w * 2 + 1;

    const char* kgA = (const char*)kb + (size_t)(c0 * 8 + lrow) * (NKV * HD * 2)
                      + hkv * (HD * 2) + swzb;
    const char* kgB = kgA + 8 * (NKV * HD * 2);
    const char* vgA = (const char*)vtb + (size_t)(hkv * HD + c0 * 8 + lrow) * (L_SEQ * 2)
                      + swzb;
    const char* vgB = vgA + 8 * (size_t)(L_SEQ * 2);

    // Q fragments (A operand): row = r16, k = ks*32 + g*8 + j
    short8 aq[2];
#pragma unroll
    for (int ks = 0; ks < 2; ++ks)
        aq[ks] = *reinterpret_cast<const short8*>(
            &qb[(size_t)(qbase + r16) * CDIM + h * HD + ks * 32 + g * 8]);

    GLOAD_LDS16(kgA, (char*)Ks[0] + c0 * 1024);
    GLOAD_LDS16(kgB, (char*)Ks[0] + c1 * 1024);
    GLOAD_LDS16(vgA, (char*)Vs[0] + c0 * 1024);
    GLOAD_LDS16(vgB, (char*)Vs[0] + c1 * 1024);
    __syncthreads();

    f32x4 oacc[4] = {};
    float lsum[4] = {};

    int cur = 0;
    for (int it = 0; it < L_SEQ / 64; ++it) {
        if (it + 1 < L_SEQ / 64) {
            const size_t ko = (size_t)(it + 1) * 64 * (NKV * HD * 2);
            const size_t vo = (size_t)(it + 1) * 128;
            char* kd = (char*)Ks[cur ^ 1];
            char* vd = (char*)Vs[cur ^ 1];
            GLOAD_LDS16(kgA + ko, kd + c0 * 1024);
            GLOAD_LDS16(kgB + ko, kd + c1 * 1024);
            GLOAD_LDS16(vgA + vo, vd + c0 * 1024);
            GLOAD_LDS16(vgB + vo, vd + c1 * 1024);
        }

        const char* kt = (const char*)Ks[cur];
        const char* vt = (const char*)Vs[cur];

        // ---- S = Q K^T (8 MFMA)
        f32x4 sacc[4] = {};
        __builtin_amdgcn_s_setprio(1);
#pragma unroll
        for (int t = 0; t < 4; ++t) {
#pragma unroll
            for (int ks = 0; ks < 2; ++ks) {
                short8 bk;
                __builtin_memcpy(&bk,
                    kt + (t * 16 + r16) * 128 + ((ks * 64 + g * 16) ^ r7sw), 16);
                sacc[t] = __builtin_amdgcn_mfma_f32_16x16x32_bf16(aq[ks], bk, sacc[t], 0, 0, 0);
            }
        }
        __builtin_amdgcn_s_setprio(0);

        // ---- P = exp2(S) (no max subtraction), accumulate l, pack to LDS
#pragma unroll
        for (int j = 0; j < 4; ++j) {
            const int row = g * 4 + j;
            char* rp = myP + row * 160;
            const int sw = (row & 7) << 4;
#pragma unroll
            for (int t = 0; t < 4; ++t) {
                const float p = exp2f(sacc[t][j]);
                lsum[j] += p;
                *reinterpret_cast<short*>(rp + (((t * 16 + r16) * 2) ^ sw)) = (short)f2bf(p);
            }
        }

        // ---- O += P V (8 MFMA)
        __builtin_amdgcn_s_setprio(1);
#pragma unroll
        for (int ks = 0; ks < 2; ++ks) {
            short8 ap;
            __builtin_memcpy(&ap,
                myP + r16 * 160 + ((ks * 64 + g * 16) ^ ((r16 & 7) << 4)), 16);
#pragma unroll
            for (int t = 0; t < 4; ++t) {
                short8 bv;
                __builtin_memcpy(&bv,
                    vt + (t * 16 + r16) * 128 + ((ks * 64 + g * 16) ^ r7sw), 16);
                oacc[t] = __builtin_amdgcn_mfma_f32_16x16x32_bf16(ap, bv, oacc[t], 0, 0, 0);
            }
        }
        __builtin_amdgcn_s_setprio(0);

        __syncthreads();
        cur ^= 1;
    }

    // ---- epilogue: reduce l across the 16-lane group, normalize, store bf16
#pragma unroll
    for (int j = 0; j < 4; ++j) {
#pragma unroll
        for (int off = 1; off < 16; off <<= 1)
            lsum[j] += __shfl_xor(lsum[j], off);
        const float inv = 1.0f / lsum[j];
        const int row = qbase + g * 4 + j;
#pragma unroll
        for (int t = 0; t < 4; ++t)
            o[(size_t)row * CDIM + h * HD + t * 16 + r16] = f2bf(oacc[t][j] * inv);
    }
}

// ---------------------------------------------------------------------------
extern "C" void kernel_launch(void* const* d_in, const int* in_sizes, int n_in,
                              void* d_out, int out_size, void* d_ws, size_t ws_size,
                              hipStream_t stream) {
    const float* x   = (const float*)d_in[0];   // [4096][512]
    const float* Wq  = (const float*)d_in[1];   // [512][512]
    const float* Wk  = (const float*)d_in[2];   // [128][512]
    const float* Wv  = (const float*)d_in[3];   // [128][512]
    const float* qnw = (const float*)d_in[4];   // [64]
    const float* knw = (const float*)d_in[5];   // [64]
    const float* Wo  = (const float*)d_in[6];   // [512][512]
    float* out = (float*)d_out;                 // [4096][512] f32

    // workspace layout (~21 MB)
    char* p = (char*)d_ws;
    float*    qbuf = (float*)p;            p += (size_t)L_SEQ * CDIM * 4;        // 8 MB
    float*    kbuf = (float*)p;            p += (size_t)L_SEQ * NKV * HD * 4;    // 2 MB
    ushort_t* xb   = (ushort_t*)p;         p += (size_t)L_SEQ * CDIM * 2;        // 4 MB
    ushort_t* qb   = (ushort_t*)p;         p += (size_t)L_SEQ * CDIM * 2;        // 4 MB
    ushort_t* kb   = (ushort_t*)p;         p += (size_t)L_SEQ * NKV * HD * 2;    // 1 MB
    ushort_t* vtb  = (ushort_t*)p;         p += (size_t)L_SEQ * NKV * HD * 2;    // 1 MB
    ushort_t* wqb  = (ushort_t*)p;         p += (size_t)CDIM * CDIM * 2;         // 0.5 MB
    ushort_t* wkb  = (ushort_t*)p;         p += (size_t)NKV * HD * CDIM * 2;
    ushort_t* wvb  = (ushort_t*)p;         p += (size_t)NKV * HD * CDIM * 2;
    ushort_t* wob  = (ushort_t*)p;         p += (size_t)CDIM * CDIM * 2;
    ushort_t* abuf = (ushort_t*)qbuf;      // attn bf16 out aliases qbuf (dead by then)

    const dim3 blk(256);

    // f32 -> bf16 conversions (x + all weights)
    cvt_bf16<<<dim3(2688), blk, 0, stream>>>(x, Wq, Wk, Wv, Wo, xb, wqb, wkb, wvb, wob);

    // QKV projections (bf16 MFMA). V is produced pre-transposed: vt = Wv * x^T.
    gemm_bf16_nt<false><<<dim3(8, 64),  blk, 0, stream>>>(xb, wqb, qbuf, L_SEQ, CDIM, CDIM);
    gemm_bf16_nt<false><<<dim3(2, 64),  blk, 0, stream>>>(xb, wkb, kbuf, L_SEQ, NKV * HD, CDIM);
    gemm_bf16_nt<true ><<<dim3(64, 2),  blk, 0, stream>>>(wvb, xb, vtb, NKV * HD, L_SEQ, CDIM);

    // RMSNorm + RoPE -> bf16 (Q pre-scaled by QSCALE)
    norm_rope<<<dim3((L_SEQ * (NH + NKV)) / 4), blk, 0, stream>>>(qbuf, kbuf, qnw, knw, qb, kb);

    // Attention (bf16 MFMA, no-max softmax) -> bf16
    attn_mfma<<<dim3(L_SEQ / 64, NH), blk, 0, stream>>>(qb, kb, vtb, abuf);

    // Output projection (bf16 MFMA -> f32 out)
    gemm_bf16_nt<false><<<dim3(8, 64), blk, 0, stream>>>(abuf, wob, out, L_SEQ, CDIM, CDIM);
}

// Round 5
// 119.558 us; speedup vs baseline: 8.2890x; 1.1415x over previous
//
#include <hip/hip_runtime.h>
#include <hip/hip_bf16.h>
#include <math.h>

// Problem constants
#define L_SEQ 4096
#define CDIM  512
#define NH    8
#define NKV   2
#define HD    64
#define EPS   1e-6f
// 1/sqrt(64) * log2(e), folded into Q at norm_rope so P = exp2(S) directly
#define QSCALE 0.18033688011f
#define NSPLIT 2
#define KVSPAN (L_SEQ / NSPLIT)

using short8 = __attribute__((ext_vector_type(8))) short;
using f32x4  = __attribute__((ext_vector_type(4))) float;
typedef unsigned short ushort_t;

// RNE float -> bf16 bits
__device__ __forceinline__ ushort_t f2bf(float f) {
    union { float f; unsigned u; } c; c.f = f;
    unsigned r = c.u + 0x7FFF + ((c.u >> 16) & 1);
    return (ushort_t)(r >> 16);
}
__device__ __forceinline__ float bf2f(ushort_t u) {
    union { unsigned u; float f; } c; c.u = ((unsigned)u) << 16;
    return c.f;
}

// async global->LDS, 16B per lane; LDS dest = wave-uniform base + lane*16
#define GLOAD_LDS16(g, l)                                                  \
    __builtin_amdgcn_global_load_lds(                                      \
        (const __attribute__((address_space(1))) unsigned int*)(g),        \
        (__attribute__((address_space(3))) unsigned int*)(l), 16, 0, 0)

// aligned LDS vector read (offsets are provably 16B-aligned)
__device__ __forceinline__ short8 lds_read8(const char* p) {
    return *reinterpret_cast<const short8*>(__builtin_assume_aligned(p, 16));
}

// ---------------------------------------------------------------------------
// f32 -> bf16 conversion for x and the 4 weights (one launch).
// ---------------------------------------------------------------------------
__global__ __launch_bounds__(256) void cvt_bf16(const float* __restrict__ x,
                                                const float* __restrict__ wq,
                                                const float* __restrict__ wk,
                                                const float* __restrict__ wv,
                                                const float* __restrict__ wo,
                                                ushort_t* __restrict__ xb,
                                                ushort_t* __restrict__ wqb,
                                                ushort_t* __restrict__ wkb,
                                                ushort_t* __restrict__ wvb,
                                                ushort_t* __restrict__ wob) {
    const size_t i = ((size_t)blockIdx.x * 256 + threadIdx.x) << 2;
    const float* s; ushort_t* d; size_t o;
    if (i < 2097152)      { s = x;  d = xb;  o = i; }
    else if (i < 2359296) { s = wq; d = wqb; o = i - 2097152; }
    else if (i < 2424832) { s = wk; d = wkb; o = i - 2359296; }
    else if (i < 2490368) { s = wv; d = wvb; o = i - 2424832; }
    else                  { s = wo; d = wob; o = i - 2490368; }
    const float4 v = *reinterpret_cast<const float4*>(s + o);
    ushort_t r[4] = { f2bf(v.x), f2bf(v.y), f2bf(v.z), f2bf(v.w) };
    *reinterpret_cast<uint2*>(d + o) = *reinterpret_cast<const uint2*>(r);
}

// ---------------------------------------------------------------------------
// bf16 MFMA NT GEMM: C[M][N] = A[M][K] * B[N][K]^T, fp32 accumulate.
// BM=BN=BK=64, 256 threads (2x2 waves, 32x32 per wave), double-buffered LDS.
// ---------------------------------------------------------------------------
template<bool OUT_BF16>
__global__ __launch_bounds__(256) void gemm_bf16_nt(const ushort_t* __restrict__ A,
                                                    const ushort_t* __restrict__ B,
                                                    void* __restrict__ Cv,
                                                    int M, int N, int K) {
    __shared__ short As[2][4096];   // [64 rows][64 k] bf16, 8KB each
    __shared__ short Bs[2][4096];

    const int tid = threadIdx.x;
    const int w = tid >> 6, lane = tid & 63;
    const int g = lane >> 4, r16 = lane & 15;
    const int wr = w >> 1, wc = w & 1;
    const int m0 = blockIdx.y * 64, n0 = blockIdx.x * 64;
    const int r7sw = (r16 & 7) << 4;

    const int lrow = lane >> 3;
    const int swzb = ((lane & 7) ^ lrow) << 4;
    const int c0 = w * 2, c1 = w * 2 + 1;
    const size_t rowK2 = (size_t)K * 2;

    const char* agA = (const char*)A + (size_t)(m0 + c0 * 8 + lrow) * rowK2 + swzb;
    const char* agB = agA + 8 * rowK2;
    const char* bgA = (const char*)B + (size_t)(n0 + c0 * 8 + lrow) * rowK2 + swzb;
    const char* bgB = bgA + 8 * rowK2;

    GLOAD_LDS16(agA, (char*)As[0] + c0 * 1024);
    GLOAD_LDS16(agB, (char*)As[0] + c1 * 1024);
    GLOAD_LDS16(bgA, (char*)Bs[0] + c0 * 1024);
    GLOAD_LDS16(bgB, (char*)Bs[0] + c1 * 1024);
    __syncthreads();

    f32x4 acc[2][2] = {};
    const int NKIT = K >> 6;
    int cur = 0;
    for (int it = 0; it < NKIT; ++it) {
        if (it + 1 < NKIT) {
            const size_t ko = (size_t)(it + 1) * 128;
            char* ad = (char*)As[cur ^ 1];
            char* bd = (char*)Bs[cur ^ 1];
            GLOAD_LDS16(agA + ko, ad + c0 * 1024);
            GLOAD_LDS16(agB + ko, ad + c1 * 1024);
            GLOAD_LDS16(bgA + ko, bd + c0 * 1024);
            GLOAD_LDS16(bgB + ko, bd + c1 * 1024);
        }
        const char* at = (const char*)As[cur];
        const char* bt = (const char*)Bs[cur];

        short8 af[2][2], bfr[2][2];
#pragma unroll
        for (int t = 0; t < 2; ++t)
#pragma unroll
            for (int ks = 0; ks < 2; ++ks) {
                af[t][ks]  = lds_read8(at + (wr * 32 + t * 16 + r16) * 128
                                          + ((ks * 64 + g * 16) ^ r7sw));
                bfr[t][ks] = lds_read8(bt + (wc * 32 + t * 16 + r16) * 128
                                          + ((ks * 64 + g * 16) ^ r7sw));
            }
        __builtin_amdgcn_s_setprio(1);
#pragma unroll
        for (int tm = 0; tm < 2; ++tm)
#pragma unroll
            for (int tn = 0; tn < 2; ++tn)
#pragma unroll
                for (int ks = 0; ks < 2; ++ks)
                    acc[tm][tn] = __builtin_amdgcn_mfma_f32_16x16x32_bf16(
                        af[tm][ks], bfr[tn][ks], acc[tm][tn], 0, 0, 0);
        __builtin_amdgcn_s_setprio(0);

        __syncthreads();
        cur ^= 1;
    }

#pragma unroll
    for (int tm = 0; tm < 2; ++tm)
#pragma unroll
        for (int tn = 0; tn < 2; ++tn)
#pragma unroll
            for (int jj = 0; jj < 4; ++jj) {
                const int row = m0 + wr * 32 + tm * 16 + g * 4 + jj;
                const int col = n0 + wc * 32 + tn * 16 + r16;
                if (OUT_BF16)
                    ((ushort_t*)Cv)[(size_t)row * N + col] = f2bf(acc[tm][tn][jj]);
                else
                    ((float*)Cv)[(size_t)row * N + col] = acc[tm][tn][jj];
            }
}

// ---------------------------------------------------------------------------
// Fused RMSNorm + RoPE; reads fp32 q/k, writes bf16 q/k (Q pre-scaled).
// ---------------------------------------------------------------------------
__global__ __launch_bounds__(256) void norm_rope(const float* __restrict__ q,
                                                 const float* __restrict__ k,
                                                 const float* __restrict__ qw,
                                                 const float* __restrict__ kw,
                                                 ushort_t* __restrict__ qb,
                                                 ushort_t* __restrict__ kb) {
    const int wid  = threadIdx.x >> 6;
    const int lane = threadIdx.x & 63;
    const long row = (long)blockIdx.x * 4 + wid;
    const long QROWS = (long)L_SEQ * NH;

    const float* ptr;
    ushort_t* optr;
    const float* w;
    int pos;
    const bool isq = (row < QROWS);
    if (isq) {
        pos = (int)(row >> 3);
        const size_t off = (size_t)pos * (NH * HD) + (int)(row & 7) * HD;
        ptr = q + off; optr = qb + off;
        w = qw;
    } else {
        const long r = row - QROWS;
        pos = (int)(r >> 1);
        const size_t off = (size_t)pos * (NKV * HD) + (int)(r & 1) * HD;
        ptr = k + off; optr = kb + off;
        w = kw;
    }

    float x = ptr[lane];
    float ss = x * x;
#pragma unroll
    for (int off = 32; off; off >>= 1) ss += __shfl_xor(ss, off);
    float xn = x * rsqrtf(ss * (1.0f / 64.0f) + EPS) * w[lane];

    float xp = __shfl_xor(xn, 32);
    const int i = lane & 31;
    // inv_freq = 10000^(-i/32) = exp2(-i * log2(10000)/32)
    const float inv_freq = exp2f((float)i * -0.41524101186f);
    float s, c;
    sincosf((float)pos * inv_freq, &s, &c);
    float out = (lane < 32) ? (xn * c - xp * s) : (xn * c + xp * s);
    if (isq) out *= QSCALE;
    optr[lane] = f2bf(out);
}

// ---------------------------------------------------------------------------
// Flash attention, bf16 MFMA 16x16x32, no-max softmax, SPLIT-KV (NSPLIT).
// Each block handles 64 q-rows x one head x one KV half. Writes UNNORMALIZED
// partial O (bf16) and partial l (f32); combine kernel merges.
// ---------------------------------------------------------------------------
__global__ __launch_bounds__(256) void attn_mfma(const ushort_t* __restrict__ qb,
                                                 const ushort_t* __restrict__ kb,
                                                 const ushort_t* __restrict__ vtb,
                                                 ushort_t* __restrict__ opart,
                                                 float* __restrict__ lpart) {
    __shared__ short Ks[2][4096];           // [64 kv][64 feat] bf16
    __shared__ short Vs[2][4096];           // [64 feat][64 kv] bf16
    __shared__ short Plds[4 * 16 * 64];     // per-wave P, 16 x 128B, swizzled

    const int tid = threadIdx.x;
    const int w = tid >> 6, lane = tid & 63;
    const int g = lane >> 4, r16 = lane & 15;
    const int h = blockIdx.y, hkv = h >> 2;
    const int s = blockIdx.z;
    const int kvb = s * KVSPAN;             // base kv row of this split
    const int qbase = blockIdx.x * 64 + w * 16;

    char* myP = reinterpret_cast<char*>(Plds) + w * 2048;
    const int r7sw = (r16 & 7) << 4;

    const int lrow = lane >> 3;
    const int swzb = ((lane & 7) ^ lrow) << 4;
    const int c0 = w * 2, c1 = w * 2 + 1;

    const char* kgA = (const char*)kb + (size_t)(kvb + c0 * 8 + lrow) * (NKV * HD * 2)
                      + hkv * (HD * 2) + swzb;
    const char* kgB = kgA + 8 * (NKV * HD * 2);
    const char* vgA = (const char*)vtb + (size_t)(hkv * HD + c0 * 8 + lrow) * (L_SEQ * 2)
                      + (size_t)kvb * 2 + swzb;
    const char* vgB = vgA + 8 * (size_t)(L_SEQ * 2);

    // Q fragments (A operand): row = r16, k = ks*32 + g*8 + j
    short8 aq[2];
#pragma unroll
    for (int ks = 0; ks < 2; ++ks)
        aq[ks] = *reinterpret_cast<const short8*>(
            &qb[(size_t)(qbase + r16) * CDIM + h * HD + ks * 32 + g * 8]);

    GLOAD_LDS16(kgA, (char*)Ks[0] + c0 * 1024);
    GLOAD_LDS16(kgB, (char*)Ks[0] + c1 * 1024);
    GLOAD_LDS16(vgA, (char*)Vs[0] + c0 * 1024);
    GLOAD_LDS16(vgB, (char*)Vs[0] + c1 * 1024);
    __syncthreads();

    f32x4 oacc[4] = {};
    float lsum[4] = {};

    int cur = 0;
    for (int it = 0; it < KVSPAN / 64; ++it) {
        if (it + 1 < KVSPAN / 64) {
            const size_t ko = (size_t)(it + 1) * 64 * (NKV * HD * 2);
            const size_t vo = (size_t)(it + 1) * 128;
            char* kd = (char*)Ks[cur ^ 1];
            char* vd = (char*)Vs[cur ^ 1];
            GLOAD_LDS16(kgA + ko, kd + c0 * 1024);
            GLOAD_LDS16(kgB + ko, kd + c1 * 1024);
            GLOAD_LDS16(vgA + vo, vd + c0 * 1024);
            GLOAD_LDS16(vgB + vo, vd + c1 * 1024);
        }

        const char* kt = (const char*)Ks[cur];
        const char* vt = (const char*)Vs[cur];

        // ---- S = Q K^T (8 MFMA)
        f32x4 sacc[4] = {};
        __builtin_amdgcn_s_setprio(1);
#pragma unroll
        for (int t = 0; t < 4; ++t) {
#pragma unroll
            for (int ks = 0; ks < 2; ++ks) {
                const short8 bk = lds_read8(
                    kt + (t * 16 + r16) * 128 + ((ks * 64 + g * 16) ^ r7sw));
                sacc[t] = __builtin_amdgcn_mfma_f32_16x16x32_bf16(aq[ks], bk, sacc[t], 0, 0, 0);
            }
        }
        __builtin_amdgcn_s_setprio(0);

        // ---- P = exp2(S), accumulate l, pack to LDS
#pragma unroll
        for (int j = 0; j < 4; ++j) {
            const int row = g * 4 + j;
            char* rp = myP + row * 128;
            const int sw = (row & 7) << 4;
#pragma unroll
            for (int t = 0; t < 4; ++t) {
                const float p = exp2f(sacc[t][j]);
                lsum[j] += p;
                *reinterpret_cast<short*>(rp + (((t * 16 + r16) * 2) ^ sw)) = (short)f2bf(p);
            }
        }

        // ---- O += P V (8 MFMA)
        __builtin_amdgcn_s_setprio(1);
#pragma unroll
        for (int ks = 0; ks < 2; ++ks) {
            const short8 ap = lds_read8(
                myP + r16 * 128 + ((ks * 64 + g * 16) ^ r7sw));
#pragma unroll
            for (int t = 0; t < 4; ++t) {
                const short8 bv = lds_read8(
                    vt + (t * 16 + r16) * 128 + ((ks * 64 + g * 16) ^ r7sw));
                oacc[t] = __builtin_amdgcn_mfma_f32_16x16x32_bf16(ap, bv, oacc[t], 0, 0, 0);
            }
        }
        __builtin_amdgcn_s_setprio(0);

        __syncthreads();
        cur ^= 1;
    }

    // ---- epilogue: reduce l over 16-lane group; store UNNORMALIZED O + l
    ushort_t* op = opart + (size_t)s * L_SEQ * CDIM;
    float* lp = lpart + (size_t)s * L_SEQ * NH;
#pragma unroll
    for (int j = 0; j < 4; ++j) {
#pragma unroll
        for (int off = 1; off < 16; off <<= 1)
            lsum[j] += __shfl_xor(lsum[j], off);
        const int row = qbase + g * 4 + j;
#pragma unroll
        for (int t = 0; t < 4; ++t)
            op[(size_t)row * CDIM + h * HD + t * 16 + r16] = f2bf(oacc[t][j]);
        if (r16 == 0) lp[(size_t)row * NH + h] = lsum[j];
    }
}

// ---------------------------------------------------------------------------
// Combine split-KV partials: out = (O0 + O1) / (l0 + l1), bf16 out.
// ---------------------------------------------------------------------------
__global__ __launch_bounds__(256) void combine_splits(const ushort_t* __restrict__ o0,
                                                      const ushort_t* __restrict__ o1,
                                                      const float* __restrict__ l0,
                                                      const float* __restrict__ l1,
                                                      ushort_t* __restrict__ out) {
    const size_t i4 = ((size_t)blockIdx.x * 256 + threadIdx.x) << 2;
    const int row = (int)(i4 >> 9);
    const int h = (int)((i4 & 511) >> 6);
    const float inv = 1.0f / (l0[(size_t)row * NH + h] + l1[(size_t)row * NH + h]);
    ushort_t a[4], b[4], r[4];
    *reinterpret_cast<uint2*>(a) = *reinterpret_cast<const uint2*>(o0 + i4);
    *reinterpret_cast<uint2*>(b) = *reinterpret_cast<const uint2*>(o1 + i4);
#pragma unroll
    for (int j = 0; j < 4; ++j)
        r[j] = f2bf((bf2f(a[j]) + bf2f(b[j])) * inv);
    *reinterpret_cast<uint2*>(out + i4) = *reinterpret_cast<const uint2*>(r);
}

// ---------------------------------------------------------------------------
extern "C" void kernel_launch(void* const* d_in, const int* in_sizes, int n_in,
                              void* d_out, int out_size, void* d_ws, size_t ws_size,
                              hipStream_t stream) {
    const float* x   = (const float*)d_in[0];   // [4096][512]
    const float* Wq  = (const float*)d_in[1];   // [512][512]
    const float* Wk  = (const float*)d_in[2];   // [128][512]
    const float* Wv  = (const float*)d_in[3];   // [128][512]
    const float* qnw = (const float*)d_in[4];   // [64]
    const float* knw = (const float*)d_in[5];   // [64]
    const float* Wo  = (const float*)d_in[6];   // [512][512]
    float* out = (float*)d_out;                 // [4096][512] f32

    // workspace layout (~21 MB), with staged aliasing:
    //   qbuf (f32, 8MB)  --after norm_rope-->  opart (2 x 4MB bf16 partial O)
    //   kbuf (f32, 2MB)  --after norm_rope-->  lpart (2 x 128KB f32 partial l)
    //   xb   (bf16, 4MB) --after GEMMs    -->  abuf  (bf16 attn out)
    char* p = (char*)d_ws;
    float*    qbuf = (float*)p;            p += (size_t)L_SEQ * CDIM * 4;
    float*    kbuf = (float*)p;            p += (size_t)L_SEQ * NKV * HD * 4;
    ushort_t* xb   = (ushort_t*)p;         p += (size_t)L_SEQ * CDIM * 2;
    ushort_t* qb   = (ushort_t*)p;         p += (size_t)L_SEQ * CDIM * 2;
    ushort_t* kb   = (ushort_t*)p;         p += (size_t)L_SEQ * NKV * HD * 2;
    ushort_t* vtb  = (ushort_t*)p;         p += (size_t)L_SEQ * NKV * HD * 2;
    ushort_t* wqb  = (ushort_t*)p;         p += (size_t)CDIM * CDIM * 2;
    ushort_t* wkb  = (ushort_t*)p;         p += (size_t)NKV * HD * CDIM * 2;
    ushort_t* wvb  = (ushort_t*)p;         p += (size_t)NKV * HD * CDIM * 2;
    ushort_t* wob  = (ushort_t*)p;         p += (size_t)CDIM * CDIM * 2;

    ushort_t* opart = (ushort_t*)qbuf;     // 2 splits x [4096][512] bf16
    float*    lpart = (float*)kbuf;        // 2 splits x [4096][8] f32
    ushort_t* abuf  = (ushort_t*)xb;       // [4096][512] bf16

    const dim3 blk(256);

    // f32 -> bf16 conversions (x + all weights)
    cvt_bf16<<<dim3(2688), blk, 0, stream>>>(x, Wq, Wk, Wv, Wo, xb, wqb, wkb, wvb, wob);

    // QKV projections (bf16 MFMA). V produced pre-transposed: vt = Wv * x^T.
    gemm_bf16_nt<false><<<dim3(8, 64),  blk, 0, stream>>>(xb, wqb, qbuf, L_SEQ, CDIM, CDIM);
    gemm_bf16_nt<false><<<dim3(2, 64),  blk, 0, stream>>>(xb, wkb, kbuf, L_SEQ, NKV * HD, CDIM);
    gemm_bf16_nt<true ><<<dim3(64, 2),  blk, 0, stream>>>(wvb, xb, vtb, NKV * HD, L_SEQ, CDIM);

    // RMSNorm + RoPE -> bf16 (Q pre-scaled by QSCALE)
    norm_rope<<<dim3((L_SEQ * (NH + NKV)) / 4), blk, 0, stream>>>(qbuf, kbuf, qnw, knw, qb, kb);

    // Attention: split-KV x2, unnormalized partials
    attn_mfma<<<dim3(L_SEQ / 64, NH, NSPLIT), blk, 0, stream>>>(qb, kb, vtb, opart, lpart);

    // Combine partials -> bf16 attn out
    combine_splits<<<dim3((L_SEQ * CDIM) / (256 * 4)), blk, 0, stream>>>(
        opart, opart + (size_t)L_SEQ * CDIM,
        lpart, lpart + (size_t)L_SEQ * NH, abuf);

    // Output projection (bf16 MFMA -> f32 out)
    gemm_bf16_nt<false><<<dim3(8, 64), blk, 0, stream>>>(abuf, wob, out, L_SEQ, CDIM, CDIM);
}